// Round 9
// baseline (94.597 us; speedup 1.0000x reference)
//
#include <hip/hip_runtime.h>

#define H_IN   181
#define W_IN   360
#define NLAT   361
#define NLON   720
#define CIN    16
#define COUT   16
#define KSZ    3
#define NNZ    8192
#define HW     (H_IN * W_IN)               // 65160
#define KHW    (KSZ * HW)                  // 195480 half8-elems per half-slice
#define MAXB   48                          // per (ho,parity) capacity (mean 11.3)
#define NMIX_BLK 768                       // 3 k-planes x 256 chunks (k = bid>>8)
#define XW_BYTES ((size_t)2 * KHW * 16)    // 6,255,360 B f16 8ch-packed

// Round 9 = round 8 with the cvt_pkrtz return-type fix (builtin returns
// __fp16 ext_vector(2); bit-cast via union instead of typed init).
// Mechanism under test: xw stored as F16 -> K2's 8 unpack VALU ops per
// entry (~40% of gather loop issue) become v_fma_mix_f32 mixed-precision
// FMAs; K1 packs with single v_cvt_pkrtz_f16_f32. f16 RTZ (2^-10 rel)
// also beats bf16 RTE (2^-8): absmax should drop ~4x.

static __device__ __forceinline__ unsigned int pkh2(float a, float b) {
    union { decltype(__builtin_amdgcn_cvt_pkrtz(0.f, 0.f)) h; unsigned int u; } cvt;
    cvt.h = __builtin_amdgcn_cvt_pkrtz(a, b);   // D[15:0]=f16(a), D[31:16]=f16(b)
    return cvt.u;
}
static __device__ __forceinline__ int rfl_i(int i) {
    return __builtin_amdgcn_readfirstlane(i);
}
static __device__ __forceinline__ float rfl_f(float f) {
    return __uint_as_float(__builtin_amdgcn_readfirstlane(__float_as_uint(f)));
}
__device__ __forceinline__ void fma4(float4& a, float v, const float4& f) {
    a.x += v * f.x; a.y += v * f.y; a.z += v * f.z; a.w += v * f.w;
}
// 8 f16 channels -> 8 mixed-precision FMAs (v_fma_mix_f32, no unpack ops)
static __device__ __forceinline__ void fma8h(float4& aL, float4& aH, float v, uint4 d) {
    union U { unsigned int u; _Float16 h[2]; };
    U u0, u1, u2, u3;
    u0.u = d.x; u1.u = d.y; u2.u = d.z; u3.u = d.w;
    aL.x += v * (float)u0.h[0]; aL.y += v * (float)u0.h[1];
    aL.z += v * (float)u1.h[0]; aL.w += v * (float)u1.h[1];
    aH.x += v * (float)u2.h[0]; aH.y += v * (float)u2.h[1];
    aH.z += v * (float)u3.h[0]; aH.w += v * (float)u3.h[1];
}

// ---------------------------------------------------------------------------
// K1: blocks [0,768) channel-mix one (k, 256-chunk) into f16 8ch-packed xw;
// blocks [768, 768+361) build latitude ho's parity-sorted packed segments.
// ---------------------------------------------------------------------------
__global__ __launch_bounds__(256) void mix_bucket_kernel(
    const float* __restrict__ x,      // [CIN][H_IN][W_IN]
    const float* __restrict__ w,      // [COUT][CIN][KSZ]
    const int*   __restrict__ ker_idx,
    const int*   __restrict__ row_idx,
    const int*   __restrict__ col_idx,
    const float* __restrict__ vals,
    uint4* __restrict__ xw8,          // [2][KSZ*H*W] 8 f16 channels per elem
    int*   __restrict__ gcnt,         // [NLAT][2] padded counts
    int4*  __restrict__ gseg)         // [NLAT][2][MAXB] {base, ps, valbits, 0}
{
    const int tid = threadIdx.x;

    if (blockIdx.x >= NMIX_BLK) {
        // ---- parity-sorted packed bucket build for latitude ho ----
        const int ho = blockIdx.x - NMIX_BLK;
        __shared__ int   s_cnt[2];
        __shared__ int   s_b [2 * MAXB];
        __shared__ int   s_ps[2 * MAXB];
        __shared__ float s_v [2 * MAXB];

        if (tid < 2) s_cnt[tid] = 0;
        if (tid < 2 * MAXB) { s_b[tid] = 0; s_ps[tid] = 0; s_v[tid] = 0.f; }
        __syncthreads();

        const int cbase = ho * NLON;
        const int4* __restrict__ col4 = (const int4*)col_idx;
        for (int n4 = tid; n4 < NNZ / 4; n4 += 256) {
            const int4 c4 = col4[n4];
#pragma unroll
            for (int j = 0; j < 4; ++j) {
                const int c = (j == 0) ? c4.x : (j == 1) ? c4.y : (j == 2) ? c4.z : c4.w;
                const unsigned d = (unsigned)(c - cbase);   // <720 iff lat==ho
                if (d < (unsigned)NLON) {
                    const int n    = 4 * n4 + j;
                    const int pe   = (int)(d & 1u);
                    const int slot = atomicAdd(&s_cnt[pe], 1);
                    if (slot < MAXB) {
                        // base in half8 units: (k*H + row)*W
                        s_b [pe * MAXB + slot] = (ker_idx[n] * H_IN + row_idx[n]) * W_IN;
                        s_ps[pe * MAXB + slot] = (int)(d >> 1);
                        s_v [pe * MAXB + slot] = vals[n];
                    }
                }
            }
        }
        __syncthreads();
        if (tid < 2) {
            int c = s_cnt[tid] < MAXB ? s_cnt[tid] : MAXB;
            gcnt[ho * 2 + tid] = (c + 3) & ~3;   // x4-padded; pad slots are zero
        }
        for (int i = tid; i < 2 * MAXB; i += 256)
            gseg[ho * 2 * MAXB + i] =
                make_int4(s_b[i], s_ps[i], __float_as_int(s_v[i]), 0);
        return;
    }

    // ---- channel mix for one (k, chunk): k is block-uniform ----
    const int k   = blockIdx.x >> 8;          // 0..2
    const int pos = (blockIdx.x & 255) * 256 + tid;

    __shared__ float sw[CIN * COUT];          // this k's slice, layout [c][co]
    {
        const int co = tid & 15, c = tid >> 4;
        sw[tid] = w[(co * CIN + c) * KSZ + k];
    }
    __syncthreads();

    if (pos >= HW) return;

    float4 a0 = make_float4(0.f, 0.f, 0.f, 0.f), a1 = a0, a2 = a0, a3 = a0;
#pragma unroll
    for (int c = 0; c < CIN; ++c) {
        const float xv = x[c * HW + pos];
        const float4* wr = (const float4*)(sw + c * COUT);   // broadcast b128
        fma4(a0, xv, wr[0]); fma4(a1, xv, wr[1]);
        fma4(a2, xv, wr[2]); fma4(a3, xv, wr[3]);
    }

    const int e = k * HW + pos;               // elem index within a half-slice
    uint4 u;
    u.x = pkh2(a0.x, a0.y); u.y = pkh2(a0.z, a0.w);
    u.z = pkh2(a1.x, a1.y); u.w = pkh2(a1.z, a1.w);
    xw8[0 * KHW + e] = u;                     // channels 0..7
    u.x = pkh2(a2.x, a2.y); u.y = pkh2(a2.z, a2.w);
    u.z = pkh2(a3.x, a3.y); u.w = pkh2(a3.z, a3.w);
    xw8[1 * KHW + e] = u;                     // channels 8..15
}

// ---------------------------------------------------------------------------
// K2: gather. grid = 722 (ho, ch-half). Thread t owns lon pair (2t, 2t+1),
// 8 channels. Per entry: one 16B dwordx4 load + 8 v_fma_mix_f32 (no unpack);
// x4 entry unroll = 4 loads in flight; metadata int4-staged in LDS, rfl->SGPR.
// ---------------------------------------------------------------------------
__global__ __launch_bounds__(384) void gather_kernel(
    const uint4* __restrict__ xw8,    // [2][KSZ*H*W] 8 f16 channels
    const float* __restrict__ bias,   // [COUT]
    const int*   __restrict__ gcnt,
    const int4*  __restrict__ gseg,
    float* __restrict__ out)          // [COUT][NLAT][NLON]
{
    const int bid = blockIdx.x;             // [0, 722)
    const int h   = bid & 1;                // channel half
    const int ho  = bid >> 1;
    const int tid = threadIdx.x;

    __shared__ int4 s_seg[2 * MAXB];
    if (tid < 2 * MAXB) s_seg[tid] = gseg[ho * 2 * MAXB + tid];
    __syncthreads();

    const int2 cnt2 = ((const int2*)gcnt)[ho];
    const int cntE = rfl_i(cnt2.x);
    const int cntO = rfl_i(cnt2.y);

    if (tid >= 360) return;
    const int t = tid;                      // lon pair (2t, 2t+1)

    const float4 bL = ((const float4*)bias)[2 * h];
    const float4 bH = ((const float4*)bias)[2 * h + 1];
    float4 accEL = bL, accEH = bH, accOL = bL, accOH = bH;
    const uint4* __restrict__ slice = xw8 + (size_t)h * KHW;

    // x4-unrolled parity segment: counts are multiples of 4, pads have v=0
#define SEG(PE, CNT, ACCL, ACCH)                                                \
    for (int e = 0; e < (CNT); e += 4) {                                        \
        const int4 s0 = s_seg[(PE) * MAXB + e + 0];                             \
        const int4 s1 = s_seg[(PE) * MAXB + e + 1];                             \
        const int4 s2 = s_seg[(PE) * MAXB + e + 2];                             \
        const int4 s3 = s_seg[(PE) * MAXB + e + 3];                             \
        const int   b0 = rfl_i(s0.x), b1 = rfl_i(s1.x);                         \
        const int   b2 = rfl_i(s2.x), b3 = rfl_i(s3.x);                         \
        const int   p0 = rfl_i(s0.y), p1 = rfl_i(s1.y);                         \
        const int   p2 = rfl_i(s2.y), p3 = rfl_i(s3.y);                         \
        const float v0 = rfl_f(__int_as_float(s0.z));                           \
        const float v1 = rfl_f(__int_as_float(s1.z));                           \
        const float v2 = rfl_f(__int_as_float(s2.z));                           \
        const float v3 = rfl_f(__int_as_float(s3.z));                           \
        int y0 = t - p0; y0 += (y0 >> 31) & 360;                                \
        int y1 = t - p1; y1 += (y1 >> 31) & 360;                                \
        int y2 = t - p2; y2 += (y2 >> 31) & 360;                                \
        int y3 = t - p3; y3 += (y3 >> 31) & 360;                                \
        const uint4 f0 = slice[b0 + y0];                                        \
        const uint4 f1 = slice[b1 + y1];                                        \
        const uint4 f2 = slice[b2 + y2];                                        \
        const uint4 f3 = slice[b3 + y3];                                        \
        fma8h(ACCL, ACCH, v0, f0); fma8h(ACCL, ACCH, v1, f1);                   \
        fma8h(ACCL, ACCH, v2, f2); fma8h(ACCL, ACCH, v3, f3);                   \
    }

    SEG(0, cntE, accEL, accEH)
    SEG(1, cntO, accOL, accOH)
#undef SEG

    const float2 rr[8] = {
        make_float2(accEL.x, accOL.x), make_float2(accEL.y, accOL.y),
        make_float2(accEL.z, accOL.z), make_float2(accEL.w, accOL.w),
        make_float2(accEH.x, accOH.x), make_float2(accEH.y, accOH.y),
        make_float2(accEH.z, accOH.z), make_float2(accEH.w, accOH.w) };
#pragma unroll
    for (int j = 0; j < 8; ++j) {
        const int co = 8 * h + j;
        *(float2*)(out + ((size_t)co * NLAT + ho) * NLON + 2 * t) = rr[j];
    }
}

// ---------------------------------------------------------------------------
extern "C" void kernel_launch(void* const* d_in, const int* in_sizes, int n_in,
                              void* d_out, int out_size, void* d_ws, size_t ws_size,
                              hipStream_t stream) {
    const float* x       = (const float*)d_in[0];
    const float* weight  = (const float*)d_in[1];
    const float* bias    = (const float*)d_in[2];
    const int*   ker_idx = (const int*)d_in[3];
    const int*   row_idx = (const int*)d_in[4];
    const int*   col_idx = (const int*)d_in[5];
    const float* vals    = (const float*)d_in[6];
    float* out = (float*)d_out;

    // workspace layout (poison fill is unconditional -> ws use is free)
    uint4* xw8  = (uint4*)d_ws;                             // 6,255,360 B
    int*   gcnt = (int*)((char*)d_ws + XW_BYTES);           // [NLAT*2]
    int4*  gseg = (int4*)((char*)d_ws + XW_BYTES + 4096);   // [NLAT*2*MAXB]

    mix_bucket_kernel<<<NMIX_BLK + NLAT, 256, 0, stream>>>(
        x, weight, ker_idx, row_idx, col_idx, vals, xw8, gcnt, gseg);
    gather_kernel<<<NLAT * 2, 384, 0, stream>>>(xw8, bias, gcnt, gseg, out);
}